// Round 9
// baseline (277.134 us; speedup 1.0000x reference)
//
#include <hip/hip_runtime.h>
#include <hip/hip_bf16.h>
#include <math.h>

// Problem constants
#define BATCH 1024
#define FEAT  2048
#define NCLS  11003
#define NPAD  11008      // 86 * 128
#define NT1   86         // N tiles for gemm1
#define NPART (NT1 * 2)  // psum partials per row (2 waves in N per tile)
#define M1    2048       // stacked [v; t]
#define C_SCALE  28.0f
#define C_ALPHA  0.6f
#define C_BETA   0.4f
#define C_SPOS   10.0f
#define C_SNEG   40.0f
#define XSCALE   16.0f              // Xn pre-scale into e4m3 normal range
#define SCL1     (C_SCALE / XSCALE) // logit = SCL1 * rcol * acc
#define SIMSCL   (1.0f / (XSCALE * XSCALE))
#define SCALE1   0x7F7F7F7F         // packed E8M0 = 1.0 in every byte

typedef float floatx4 __attribute__((ext_vector_type(4)));
typedef float f32x16  __attribute__((ext_vector_type(16)));
typedef int   v8i     __attribute__((ext_vector_type(8)));
typedef unsigned char u8;

// ---- workspace layout (bytes) ----
#define O_ALIGN  ((size_t)0)         // f32 align_sum
#define O_INST   ((size_t)64)        // f32 instance-CE sum
#define O_FIN    ((size_t)128)       // int fin counter (merge blocks)
#define O_COLSQ  ((size_t)256)       // NPAD f32  (ends 44288)
#define O_XN     ((size_t)44288)     // 2048*2048 fp8 (normalized [v;t], x16)
#define O_WT     ((size_t)4238592)   // NPAD*2048 fp8 (W^T, raw values)
#define O_PSUM   ((size_t)26782976)  // 2048*NPART f32
#define O_LL     ((size_t)28192000)  // 2048 f32 label logits
// zeroed prefix: [0, O_XN)

#define PREP_WBLOCKS (43 * 16)       // 688: 256-class x 128-feature tiles
#define PREP_XBLOCKS 512             // 4 rows/block, 1 wave/row
#define PREP_TOTAL   (PREP_WBLOCKS + PREP_XBLOCKS)

#define MERGE_BLOCKS 256
#define ROWS_PER_MB  (M1 / MERGE_BLOCKS)  // 8

__device__ inline float softplusf(float x) {
    return (x > 20.f) ? x : log1pf(expf(x));
}

// async 16B global -> LDS (wave-uniform base + lane*16; layout is lane-linear)
__device__ inline void gll16(const void* g, void* l) {
    __builtin_amdgcn_global_load_lds(
        (const __attribute__((address_space(1))) unsigned int*)g,
        (__attribute__((address_space(3))) unsigned int*)l, 16, 0, 0);
}

__device__ inline unsigned int pack4_fp8(float a, float b, float c, float d) {
    unsigned int p = __builtin_amdgcn_cvt_pk_fp8_f32(a, b, 0, false);
    p = __builtin_amdgcn_cvt_pk_fp8_f32(c, d, p, true);
    return p;  // bytes: a,b,c,d
}

// XOR swizzle on 16B-chunk index (self-inverse). R5 LESSON: swz does NOT
// distribute over addition in the chunk-within-row bits. ALWAYS apply swz to
// the COMPLETE logical chunk index; never fold deltas onto a swizzled base.
__device__ inline int swz(int c) { return c ^ ((c >> 4) & 7); }

// ---------------- fused prep (unchanged from R8) ----------------
__global__ __launch_bounds__(256) void k_prep(const float* __restrict__ vis,
                                              const float* __restrict__ txt,
                                              const float* __restrict__ W,
                                              u8* __restrict__ Xn,
                                              u8* __restrict__ WT,
                                              float* __restrict__ colsq) {
    __shared__ u8 tileT[2048 * 16];     // 32 KB: 2048 16B chunks (class x f-chunk)
    __shared__ float cps[4][256];
    int t = threadIdx.x;
    if (blockIdx.x < PREP_WBLOCKS) {
        int c0 = (blockIdx.x % 43) * 256, f0 = (blockIdx.x / 43) * 128;
        int w = t >> 6, l = t & 63;
        int cbase = c0 + 4 * l;              // this thread's 4 classes
        unsigned int chunks[4][8];           // [class j][feature-quad q]
        float ssq0 = 0.f, ssq1 = 0.f, ssq2 = 0.f, ssq3 = 0.f;
        #pragma unroll
        for (int q = 0; q < 8; ++q) {
            float4 row[4];
            #pragma unroll
            for (int rr = 0; rr < 4; ++rr) {
                int f = f0 + w * 32 + q * 4 + rr;
                const float* p = W + (size_t)f * NCLS + cbase;
                float4 v;
                if (cbase + 3 < NCLS) {
                    __builtin_memcpy(&v, p, 16);   // HW unaligned global load
                } else {
                    v.x = (cbase + 0 < NCLS) ? p[0] : 0.f;
                    v.y = (cbase + 1 < NCLS) ? p[1] : 0.f;
                    v.z = (cbase + 2 < NCLS) ? p[2] : 0.f;
                    v.w = (cbase + 3 < NCLS) ? p[3] : 0.f;
                }
                row[rr] = v;
            }
            chunks[0][q] = pack4_fp8(row[0].x, row[1].x, row[2].x, row[3].x);
            chunks[1][q] = pack4_fp8(row[0].y, row[1].y, row[2].y, row[3].y);
            chunks[2][q] = pack4_fp8(row[0].z, row[1].z, row[2].z, row[3].z);
            chunks[3][q] = pack4_fp8(row[0].w, row[1].w, row[2].w, row[3].w);
            #pragma unroll
            for (int rr = 0; rr < 4; ++rr) {
                ssq0 += row[rr].x * row[rr].x;
                ssq1 += row[rr].y * row[rr].y;
                ssq2 += row[rr].z * row[rr].z;
                ssq3 += row[rr].w * row[rr].w;
            }
        }
        // LDS transpose: logical chunk = class-local*8 + h, h = 16-feature
        // chunk (this wave produces h = 2w, 2w+1); stored at XOR-swizzled idx.
        #pragma unroll
        for (int j = 0; j < 4; ++j) {
            #pragma unroll
            for (int e = 0; e < 2; ++e) {
                int L = (4 * l + j) * 8 + 2 * w + e;
                int P = L ^ ((L >> 4) & 7);
                *(uint4*)(tileT + P * 16) =
                    make_uint4(chunks[j][4*e+0], chunks[j][4*e+1],
                               chunks[j][4*e+2], chunks[j][4*e+3]);
            }
        }
        *(float4*)&cps[w][4 * l] = make_float4(ssq0, ssq1, ssq2, ssq3);
        __syncthreads();
        int c = c0 + t;
        uint4* dst = (uint4*)(WT + (size_t)c * FEAT + f0);
        #pragma unroll
        for (int w2 = 0; w2 < 8; ++w2) {
            int L = t * 8 + w2;
            int P = L ^ ((L >> 4) & 7);
            dst[w2] = *(const uint4*)(tileT + P * 16);
        }
        float s = cps[0][t] + cps[1][t] + cps[2][t] + cps[3][t];
        if (c < NCLS) atomicAdd(&colsq[c], s);
    } else {
        // X normalize: wave w handles row r; lane owns 8 float4 (32 floats).
        int w = t >> 6, l = t & 63;
        int r = (blockIdx.x - PREP_WBLOCKS) * 4 + w;
        const float* src = (r < BATCH) ? (vis + (size_t)r * FEAT)
                                       : (txt + (size_t)(r - BATCH) * FEAT);
        float4 v[8];
        float ss = 0.f;
        #pragma unroll
        for (int k = 0; k < 8; ++k) {
            v[k] = ((const float4*)src)[l + 64 * k];
            ss += v[k].x*v[k].x + v[k].y*v[k].y + v[k].z*v[k].z + v[k].w*v[k].w;
        }
        #pragma unroll
        for (int off = 1; off < 64; off <<= 1) ss += __shfl_xor(ss, off);
        float rn = rsqrtf(ss) * XSCALE;
        unsigned int* dst = (unsigned int*)(Xn + (size_t)r * FEAT);
        #pragma unroll
        for (int k = 0; k < 8; ++k)
            dst[l + 64 * k] = pack4_fp8(v[k].x*rn, v[k].y*rn, v[k].z*rn, v[k].w*rn);
    }
}

// ---------------- fused GEMM: lse tiles (y<86) + sim tiles (y>=86) ----------------
// R9: register diet -> 4 waves/SIMD. Same R6 schedule (proven 87 µs), but:
//  * A/B staging share ONE 32-bit offset vector voff[4] against two uniform
//    bases (A and B have identical per-q row/chunk patterns) — was 16 ptr VGPRs.
//  * LDS read addrs recomputed per ks-iter with full swz() (R5 lesson), not
//    16 live pointers.
//  * __launch_bounds__(256, 4): 64 AGPR acc + <=64 VGPR = 128 regs/wave
//    -> 4 waves/SIMD (was 140 regs -> 3). Inter-wave overlap is the ONLY
//    latency-hiding mechanism here (R1/R2), so +33% waves ~ linear gain.
// HISTORY — do not retry:
//  * R1/R2: explicit LDS dbuf + raw s_barrier + vmcnt(0) -> 2x SLOWER.
//  * R3: XCD-chunked work swizzle -> FETCH halved but 2.2x SLOWER.
//  * R5: folding ks/cc deltas onto swizzled base -> WRONG ROW reads, NaN.
//  * R7: 256x128 tile -> occupancy collapse (10.7%), 1.35x SLOWER.
// A frag: row=lane&31, K-half=lane>>5, 32 bytes.
// C/D: col=lane&31, row=(reg&3)+8*(reg>>2)+4*(lane>>5).
// LDS layout: logical chunk = row*8 + h (16B chunks, 8/row = 128B = BK fp8),
// stored at chunk swz(logical).
__global__ __launch_bounds__(256, 4) void k_gemm(const u8* __restrict__ Xn,
                                              const u8* __restrict__ WT,
                                              const float* __restrict__ colsq,
                                              const int* __restrict__ labels,
                                              float* __restrict__ psum,
                                              float* __restrict__ ll,
                                              float* __restrict__ align_sum) {
    __shared__ u8 As[128 * 128], Bs[128 * 128];   // 16 KB + 16 KB
    f32x16 acc[2][2] = {};
    const int t = threadIdx.x;
    const bool is_sim = (blockIdx.y >= NT1);
    int m0, n0;
    const u8 *Abase, *Bbase;
    if (!is_sim) {
        m0 = blockIdx.x * 128; n0 = blockIdx.y * 128;
        Abase = Xn + (size_t)m0 * FEAT;
        Bbase = WT + (size_t)n0 * FEAT;
    } else {
        int s = (blockIdx.y - NT1) * 16 + blockIdx.x;   // 0..63
        m0 = (s >> 3) * 128; n0 = (s & 7) * 128;
        Abase = Xn + (size_t)m0 * FEAT;
        Bbase = Xn + (size_t)(BATCH + n0) * FEAT;
    }
    // staging: thread t owns LDS chunks {t, 256+t, 512+t, 768+t} (lane-linear
    // per gll16); global source chunk is the inverse-swizzle. A and B use the
    // SAME per-lane offsets (voff) against their uniform bases.
    unsigned voff[4];
    #pragma unroll
    for (int q = 0; q < 4; ++q) {
        int L = swz(q * 256 + t);
        voff[q] = (unsigned)((L >> 3) * FEAT + (L & 7) * 16);
    }

    const int wave = t >> 6, lane = t & 63;
    const int wm = wave >> 1, wn = wave & 1;
    const int l32 = lane & 31, kh = lane >> 5;

    for (int kt = 0; kt < FEAT / 128; ++kt) {
        __syncthreads();
        #pragma unroll
        for (int q = 0; q < 4; ++q) {
            gll16(Abase + voff[q], As + (q * 256 + t) * 16);
            gll16(Bbase + voff[q], Bs + (q * 256 + t) * 16);
        }
        #pragma unroll
        for (int q = 0; q < 4; ++q) voff[q] += 128;
        __syncthreads();
        #pragma unroll
        for (int ks = 0; ks < 2; ++ks) {
            v8i a[2], b[2];
            #pragma unroll
            for (int i = 0; i < 2; ++i) {
                int ca = (wm*64 + i*32 + l32) * 8 + ks*4 + kh*2;  // bit0 = 0
                int cb = (wn*64 + i*32 + l32) * 8 + ks*4 + kh*2;
                ((uint4*)&a[i])[0] = *(const uint4*)(As + swz(ca) * 16);
                ((uint4*)&a[i])[1] = *(const uint4*)(As + swz(ca + 1) * 16);
                ((uint4*)&b[i])[0] = *(const uint4*)(Bs + swz(cb) * 16);
                ((uint4*)&b[i])[1] = *(const uint4*)(Bs + swz(cb + 1) * 16);
            }
            #pragma unroll
            for (int i = 0; i < 2; ++i)
                #pragma unroll
                for (int j = 0; j < 2; ++j)
                    acc[i][j] = __builtin_amdgcn_mfma_scale_f32_32x32x64_f8f6f4(
                        a[i], b[j], acc[i][j], 0, 0, 0, SCALE1, 0, SCALE1);
        }
    }

    if (!is_sim) {
        // ---- LSE epilogue: fixed-max sum of exp(logit - 28) + label-logit scatter ----
        float rcol[2]; bool val[2]; int ncol[2];
        #pragma unroll
        for (int j = 0; j < 2; ++j) {
            ncol[j] = n0 + wn*64 + j*32 + l32;
            val[j] = (ncol[j] < NCLS);
            rcol[j] = val[j] ? (SCL1 * rsqrtf(colsq[ncol[j]])) : 0.f;
        }
        const int pidx = blockIdx.y * 2 + wn;
        #pragma unroll
        for (int i = 0; i < 2; ++i) {
            #pragma unroll
            for (int reg = 0; reg < 16; ++reg) {
                int m = m0 + wm*64 + i*32 + (reg & 3) + 8*(reg >> 2) + 4*kh;
                int lm = labels[m & (BATCH - 1)];
                float s = 0.f;
                #pragma unroll
                for (int j = 0; j < 2; ++j) {
                    if (val[j]) {
                        float v = acc[i][j][reg] * rcol[j];
                        if (ncol[j] == lm) ll[m] = v;
                        s += __expf(v - C_SCALE);
                    }
                }
                #pragma unroll
                for (int off = 1; off < 32; off <<= 1) s += __shfl_xor(s, off);
                if (l32 == 0) psum[(size_t)m * NPART + pidx] = s;
            }
        }
    } else {
        // ---- sim epilogue: masked softplus sum ----
        int ln[2];
        #pragma unroll
        for (int j = 0; j < 2; ++j) ln[j] = labels[n0 + wn*64 + j*32 + l32];
        float tot = 0.f;
        #pragma unroll
        for (int i = 0; i < 2; ++i) {
            #pragma unroll
            for (int reg = 0; reg < 16; ++reg) {
                int m = m0 + wm*64 + i*32 + (reg & 3) + 8*(reg >> 2) + 4*kh;
                int lm = labels[m];
                #pragma unroll
                for (int j = 0; j < 2; ++j) {
                    float s = acc[i][j][reg] * SIMSCL;
                    float arg = (lm == ln[j]) ? (-C_SPOS * (s - C_ALPHA))
                                              : ( C_SNEG * (s - C_BETA));
                    tot += softplusf(arg);
                }
            }
        }
        #pragma unroll
        for (int off = 1; off < 64; off <<= 1) tot += __shfl_xor(tot, off);
        if (lane == 0) atomicAdd(align_sum, tot);
    }
}

// ---------------- merge psum partials -> CE sum; last block writes out ----------------
// R3-proven: 256 blocks x 8 rows, ONE same-address atomicAdd per block.
__global__ __launch_bounds__(256) void k_merge(const float* __restrict__ psum,
                                               const float* __restrict__ ll,
                                               float* __restrict__ inst_sum,
                                               const float* __restrict__ align_sum,
                                               int* __restrict__ fin,
                                               float* __restrict__ out) {
    const int t = threadIdx.x;
    const int g = t >> 5, l = t & 31;             // 8 groups of 32 lanes
    const int r = blockIdx.x * ROWS_PER_MB + g;
    const float* pr = psum + (size_t)r * NPART;
    float s = 0.f;
    for (int p = l; p < NPART; p += 32) s += pr[p];
    #pragma unroll
    for (int off = 1; off < 32; off <<= 1) s += __shfl_xor(s, off);
    __shared__ float sb[ROWS_PER_MB];
    if (l == 0) sb[g] = C_SCALE + logf(s) - ll[r];
    __syncthreads();
    if (t == 0) {
        float ce = 0.f;
        #pragma unroll
        for (int i = 0; i < ROWS_PER_MB; ++i) ce += sb[i];
        atomicAdd(inst_sum, ce);
        __threadfence();
        if (atomicAdd(fin, 1) == MERGE_BLOCKS - 1) {    // last merge block
            __threadfence();
            float is = atomicAdd(inst_sum, 0.f);        // atomic read, device scope
            float as = atomicAdd((float*)align_sum, 0.f);
            out[0] = is / (float)BATCH;
            out[1] = as * 2.f / (float)BATCH;
        }
    }
}

extern "C" void kernel_launch(void* const* d_in, const int* in_sizes, int n_in,
                              void* d_out, int out_size, void* d_ws, size_t ws_size,
                              hipStream_t stream) {
    const float* vis    = (const float*)d_in[0];
    const float* txt    = (const float*)d_in[1];
    const int*   labels = (const int*)  d_in[2];
    const float* W      = (const float*)d_in[3];
    float* out = (float*)d_out;
    char*  ws  = (char*)d_ws;

    float* align_sum = (float*)(ws + O_ALIGN);
    float* inst_sum  = (float*)(ws + O_INST);
    int*   fin       = (int*)  (ws + O_FIN);
    float* colsq     = (float*)(ws + O_COLSQ);
    u8* Xn = (u8*)(ws + O_XN);
    u8* WT = (u8*)(ws + O_WT);
    float* psum = (float*)(ws + O_PSUM);
    float* ll   = (float*)(ws + O_LL);

    hipMemsetAsync(ws, 0, O_XN, stream);  // zero align/inst/fin/colsq

    k_prep <<<dim3(PREP_TOTAL), 256, 0, stream>>>(vis, txt, W, Xn, WT, colsq);
    k_gemm <<<dim3(M1 / 128, NT1 + 4), 256, 0, stream>>>(Xn, WT, colsq, labels,
                                                         psum, ll, align_sum);
    k_merge<<<dim3(MERGE_BLOCKS), 256, 0, stream>>>(psum, ll, inst_sum, align_sum,
                                                    fin, out);
}